// Round 14
// baseline (148.280 us; speedup 1.0000x reference)
//
#include <hip/hip_runtime.h>
#include <hip/hip_fp16.h>
#include <float.h>

// Batched 1D linear interpolation with clamped extrapolation.
// t: [B,N] sorted fp32, v: [B,N] fp32, r: [B,M] fp32 -> out: [B,M] fp32
constexpr int B = 2048;
constexpr int N = 4096;
constexpr int M = 4096;
constexpr int K = 4088;   // lut buckets (u16), ~1 point/bucket
constexpr int T = 1024;   // 16 waves/block; 2 blocks/CU = 32 waves/CU (full cap)
constexpr int BPB = 4;    // batches per block
constexpr int GRID = B / BPB;  // 512 = 256 CUs x 2 resident blocks, no backfill
// LDS: st[2][N+4] f32 (32800) + svh[2][N] fp16 (16384) + lut (8176) = 57360 B.
// Why this structure: phases were chip-wide lockstepped (VALU 37 + LDS ~38 +
// HBM ~25 ~= 100%, pipes time-sliced); register prefetch failed twice because
// the 64-VGPR cap makes the compiler sink the loads (R4/R12); a static stagger
// decays (R13, lockstep is an attractor). global_load_lds prefetch is tracked
// by vmcnt, NOT registers -> nothing to sink. Next batch's t streams into
// st[nxt] across fill + the whole query phase; one vmcnt(0) drain per batch.
// sv is fp16 so the double buffer fits the 64 KiB static LDS limit (R8).

__device__ __forceinline__ void gll16(const float* g, float* l) {
    __builtin_amdgcn_global_load_lds(
        (const __attribute__((address_space(1))) void*)g,
        (__attribute__((address_space(3))) void*)l, 16, 0, 0);
}
__device__ __forceinline__ void barrier_lgkm() {
    // LDS producer->consumer only: do NOT drain vmcnt (keeps GLL in flight;
    // __syncthreads() would emit s_waitcnt vmcnt(0) and kill the overlap).
    asm volatile("s_waitcnt lgkmcnt(0)" ::: "memory");
    __builtin_amdgcn_s_barrier();
}
__device__ __forceinline__ void barrier_full() {
    asm volatile("s_waitcnt vmcnt(0) lgkmcnt(0)" ::: "memory");
    __builtin_amdgcn_s_barrier();
}

__global__ __launch_bounds__(T, 8) void interp_kernel(
    const float* __restrict__ t,
    const float* __restrict__ v,
    const float* __restrict__ r,
    float* __restrict__ out) {
    __shared__ __align__(16) float st[2][N + 4];   // st[*][N..] = +inf sentinels
    __shared__ __align__(16) __half svh[2][N];     // fp16 leaf values
    __shared__ unsigned short lut[K];              // lut[k] = first j, bucket(t[j]) >= k

    const int tid = threadIdx.x;
    const int b0 = blockIdx.x * BPB;

    if (tid < 4) { st[0][N + tid] = FLT_MAX; st[1][N + tid] = FLT_MAX; }

    // Prologue: stage batch b0 into buffer 0.
    {
        const float4 vf = ((const float4*)(v + (size_t)b0 * N))[tid];
        gll16(t + (size_t)b0 * N + 4 * tid, &st[0][4 * tid]);
        const __half2 h01 = __floats2half2_rn(vf.x, vf.y);
        const __half2 h23 = __floats2half2_rn(vf.z, vf.w);
        union { __half2 h; unsigned u; } a{h01}, c{h23};
        ((uint2*)svh[0])[tid] = make_uint2(a.u, c.u);
    }
    barrier_full();

    for (int i = 0; i < BPB; ++i) {
        const int cur = i & 1;
        const int b = b0 + i;
        const float* stc = st[cur];
        const __half* svc = svh[cur];

        // Issue order matters for vmcnt FIFO: queries (oldest), next-v, GLL
        // (newest). The sv-convert below waits r+v only -> GLL stays in flight
        // across fill + the entire query phase.
        const float4 qf = ((const float4*)(r + (size_t)b * M))[tid];
        float4 vf = make_float4(0.f, 0.f, 0.f, 0.f);
        const bool more = (i + 1 < BPB);
        if (more) {
            vf = ((const float4*)(v + (size_t)(b + 1) * N))[tid];
            gll16(t + (size_t)(b + 1) * N + 4 * tid, &st[cur ^ 1][4 * tid]);
        }

        // lut range-fill from stc. Element j claims ((bucket(t[j-1]), bucket(t[j])];
        // j==0 starts at 0, j==N-1 extends to K-1 -> full coverage, no init
        // pass, disjoint -> no races. Covers the v-load latency.
        for (int j = tid; j < N; j += T) {
            const float tj = stc[j];
            int khi = (int)(tj * (float)K);
            if (khi > K - 1 || j == N - 1) khi = K - 1;
            int klo = 0;
            if (j > 0) klo = (int)(stc[j - 1] * (float)K) + 1;
            for (int k = klo; k <= khi; ++k) lut[k] = (unsigned short)j;
        }

        // Commit next batch's fp16 leaves (waits vf, not the GLL).
        if (more) {
            const __half2 h01 = __floats2half2_rn(vf.x, vf.y);
            const __half2 h23 = __floats2half2_rn(vf.z, vf.w);
            union { __half2 h; unsigned u; } a{h01}, c{h23};
            ((uint2*)svh[cur ^ 1])[tid] = make_uint2(a.u, c.u);
        }

        barrier_lgkm();   // lut + svh[nxt] visible; GLL still streaming

        // ---- R2 query phases (4 queries/thread at T=1024) ----
        const float tfirst = stc[0], tlast = stc[N - 1];
        const float vfirst = __half2float(svc[0]);
        const float vlast = __half2float(svc[N - 1]);

        float q[4] = {qf.x, qf.y, qf.z, qf.w};
        int lo[4];
        #pragma unroll
        for (int j = 0; j < 4; ++j) {
            int k = (int)(q[j] * (float)K);
            k = k < 0 ? 0 : (k > K - 1 ? K - 1 : k);
            lo[j] = lut[k];
        }
        #pragma unroll
        for (int j = 0; j < 4; ++j) {
            lo[j] += (stc[lo[j]] <= q[j]) ? 1 : 0;
            lo[j] += (stc[lo[j]] <= q[j]) ? 1 : 0;
            while (stc[lo[j]] <= q[j]) ++lo[j];   // inf sentinels bound
        }
        float o[4];
        #pragma unroll
        for (int j = 0; j < 4; ++j) {
            const int idx = lo[j] < 1 ? 1 : (lo[j] > N - 1 ? N - 1 : lo[j]);
            const float t0 = stc[idx - 1];
            const float t1 = stc[idx];
            const float v0 = __half2float(svc[idx - 1]);
            const float v1 = __half2float(svc[idx]);
            const float d = t1 - t0;
            const float rden = __builtin_amdgcn_rcpf(d == 0.0f ? 1.0f : d);
            float oo = v0 + (q[j] - t0) * rden * (v1 - v0);
            oo = (q[j] < tfirst) ? vfirst : oo;
            oo = (q[j] > tlast) ? vlast : oo;
            o[j] = oo;
        }
        ((float4*)(out + (size_t)b * M))[tid] = make_float4(o[0], o[1], o[2], o[3]);

        // One drain per batch: GLL(nxt) landed; all lut/st/sv readers done
        // before the next iteration overwrites them.
        barrier_full();
    }
}

extern "C" void kernel_launch(void* const* d_in, const int* in_sizes, int n_in,
                              void* d_out, int out_size, void* d_ws, size_t ws_size,
                              hipStream_t stream) {
    const float* t = (const float*)d_in[0];
    const float* v = (const float*)d_in[1];
    const float* r = (const float*)d_in[2];
    float* out = (float*)d_out;
    interp_kernel<<<GRID, T, 0, stream>>>(t, v, r, out);
}